// Round 12
// baseline (331.983 us; speedup 1.0000x reference)
//
#include <hip/hip_runtime.h>

#define ND   2048
#define BB   16384

typedef unsigned short u16;
typedef unsigned int u32;
typedef __attribute__((ext_vector_type(8))) short short8;
typedef __attribute__((ext_vector_type(4))) float f32x4;

__device__ inline float bf2f(u16 u) {
    union { u32 i; float f; } v; v.i = ((u32)u) << 16; return v.f;
}
__device__ inline u16 f2bf(float f) {
    union { float f; u32 i; } v; v.f = f;
    u32 i = v.i + 0x7fffu + ((v.i >> 16) & 1u);
    return (u16)(i >> 16);
}
__device__ inline float seluf(float x) {
    const float sc = 1.0507009873554805f, al = 1.6732632423543772f;
    return x > 0.f ? sc * x : sc * al * expm1f(x);
}
__device__ inline short8 packbf8(float4 f0, float4 f1) {
    short8 a;
    a[0] = (short)f2bf(f0.x); a[1] = (short)f2bf(f0.y);
    a[2] = (short)f2bf(f0.z); a[3] = (short)f2bf(f0.w);
    a[4] = (short)f2bf(f1.x); a[5] = (short)f2bf(f1.y);
    a[6] = (short)f2bf(f1.z); a[7] = (short)f2bf(f1.w);
    return a;
}

// ---------------- dtype sniffer ----------------
__global__ void detectk(const void* __restrict__ demb, u32* __restrict__ flag) {
    const u16* p = (const u16*)demb;
    int tid = threadIdx.x;  // 256
    int sane = 0;
    #pragma unroll
    for (int i = 0; i < 2; i++) {
        u16 u = p[4 * tid + 2 * i];
        int e = (u >> 7) & 0xFF;
        if (u == 0 || (e >= 0x66 && e <= 0x8C)) sane++;
    }
    __shared__ int red[256];
    red[tid] = sane; __syncthreads();
    for (int o = 128; o > 0; o >>= 1) {
        if (tid < o) red[tid] += red[tid + o];
        __syncthreads();
    }
    if (tid == 0) flag[0] = (red[0] < 300) ? 1u : 0u;
}

// ---------------- canonical bf16 conversion (26 segments, one launch) -------
#define NSEG 26
struct CvtArgs { const void* src[NSEG]; int off[NSEG]; int n[NSEG]; };

__global__ __launch_bounds__(256) void cvtk(CvtArgs a, u16* __restrict__ base,
                                            const u32* __restrict__ flag) {
    int seg = blockIdx.y;
    int n = a.n[seg];
    const void* s = a.src[seg];
    u16* d = base + a.off[seg];
    bool f32 = flag[0] != 0;
    int stride = gridDim.x * blockDim.x;
    for (int i = blockIdx.x * blockDim.x + threadIdx.x; i < n; i += stride)
        d[i] = f32 ? f2bf(((const float*)s)[i]) : ((const u16*)s)[i];
}

// ---------------- transpose (bf16, tiled 32x32) ----------------
__device__ inline void tpose_body(const u16* in, int R, int C,
                                  u16* out, int ldo, int ooff,
                                  u16 (*tile)[33]) {
    int c0 = blockIdx.x * 32, r0 = blockIdx.y * 32;
    int x = c0 + threadIdx.x;
    for (int i = threadIdx.y; i < 32; i += 8) {
        int r = r0 + i;
        tile[i][threadIdx.x] = (r < R && x < C) ? in[(size_t)r * C + x] : (u16)0;
    }
    __syncthreads();
    int rr = r0 + threadIdx.x;
    for (int i = threadIdx.y; i < 32; i += 8) {
        int cc = c0 + i;
        if (cc < C && rr < R) out[(size_t)cc * ldo + ooff + rr] = tile[threadIdx.x][i];
    }
}

__global__ void tpose_embs(const u16* __restrict__ demb, const u16* __restrict__ pemb,
                           u16* __restrict__ disT, u16* __restrict__ drugT) {
    __shared__ u16 tile[32][33];
    if (blockIdx.z == 0) tpose_body(demb, ND, 128, disT, ND, 0, tile);
    else                 tpose_body(pemb, ND, 128, drugT, ND, 0, tile);
}

__global__ void tpose_smalls(const u16* s0, const u16* s1, const u16* s2,
                             const u16* s3, const u16* s4, const u16* s5,
                             u16* W1T, u16* W2T, u16* WcTe, u16* WcTp) {
    __shared__ u16 tile[32][33];
    const u16* in; u16* out; int ldo, ooff;
    switch (blockIdx.z) {
        case 0:  in = s0; out = W1T;  ldo = 128; ooff = 0;   break;
        case 1:  in = s1; out = W2T;  ldo = 128; ooff = 0;   break;
        case 2:  in = s2; out = WcTe; ldo = 256; ooff = 0;   break;
        case 3:  in = s3; out = WcTe; ldo = 256; ooff = 128; break;
        case 4:  in = s4; out = WcTp; ldo = 256; ooff = 0;   break;
        default: in = s5; out = WcTp; ldo = 256; ooff = 128; break;
    }
    tpose_body(in, 128, 128, out, ldo, ooff, tile);
}

// ---------------- combined biases ----------------
__global__ void biasc(const u16* a0, const u16* a1, const u16* a2, u16* o0,
                      const u16* b0, const u16* b1, const u16* b2, u16* o1) {
    int t = threadIdx.x;  // 128
    o0[t] = f2bf(bf2f(a0[t]) + bf2f(a1[t]) + bf2f(a2[t]));
    o1[t] = f2bf(bf2f(b0[t]) + bf2f(b1[t]) + bf2f(b2[t]));
}

// ---------------- inverse degree ----------------
__global__ __launch_bounds__(256) void degk(
    const void* __restrict__ e_e, float* __restrict__ dinv_e,
    const void* __restrict__ p_p, float* __restrict__ dinv_p,
    const u32* __restrict__ flag) {
    int row = blockIdx.x, tid = threadIdx.x;
    const void* ab = blockIdx.y ? p_p : e_e;
    float* o = blockIdx.y ? dinv_p : dinv_e;
    bool f32 = flag[0] != 0;
    float s = 0.f;
    if (f32) {
        const float4* a4 = (const float4*)((const float*)ab + (size_t)row * 2048) + tid * 2;
        float4 v0 = a4[0], v1 = a4[1];
        s = v0.x + v0.y + v0.z + v0.w + v1.x + v1.y + v1.z + v1.w;
    } else {
        const uint4* a4 = (const uint4*)((const u16*)ab + (size_t)row * 2048) + tid;
        uint4 v = a4[0];
        u32 u[4] = {v.x, v.y, v.z, v.w};
        #pragma unroll
        for (int c = 0; c < 4; c++)
            s += bf2f((u16)(u[c] & 0xffff)) + bf2f((u16)(u[c] >> 16));
    }
    __shared__ float red[256];
    red[tid] = s; __syncthreads();
    for (int ofs = 128; ofs > 0; ofs >>= 1) {
        if (tid < ofs) red[tid] += red[tid + ofs];
        __syncthreads();
    }
    if (tid == 0) o[row] = 1.f / (red[0] + 1e-8f);
}

// ---------------- ko / qs projections ----------
__global__ __launch_bounds__(128) void koqs(
    const u16* __restrict__ demb, const u16* __restrict__ pemb,
    const u16* __restrict__ Wa1d, const u16* __restrict__ ba1d,
    const u16* __restrict__ Wa1p, const u16* __restrict__ ba1p,
    float* __restrict__ ko_d, float* __restrict__ qs_d,
    float* __restrict__ ko_p, float* __restrict__ qs_p) {
    int row = blockIdx.x, m = blockIdx.y, tid = threadIdx.x;
    const u16* src; const u16* W; const u16* bias; float* out;
    switch (m) {
        case 0:  src = pemb; W = Wa1d;            bias = nullptr; out = ko_d; break;
        case 1:  src = demb; W = Wa1d + 128 * 32; bias = ba1d;    out = qs_d; break;
        case 2:  src = demb; W = Wa1p;            bias = nullptr; out = ko_p; break;
        default: src = pemb; W = Wa1p + 128 * 32; bias = ba1p;    out = qs_p; break;
    }
    __shared__ float x[128];
    __shared__ float red[128];
    x[tid] = bf2f(src[(size_t)row * 128 + tid]);
    __syncthreads();
    int a = tid & 31, part = tid >> 5;
    float s = 0.f;
    #pragma unroll
    for (int k = 0; k < 32; k++) s += x[part * 32 + k] * bf2f(W[(part * 32 + k) * 32 + a]);
    red[tid] = s;
    __syncthreads();
    if (part == 0) {
        float t = red[a] + red[a + 32] + red[a + 64] + red[a + 96];
        if (bias) t += bf2f(bias[a]);
        out[(size_t)row * 32 + a] = t;
    }
}

// ---------------- attention v6: lane-owns-j, ko in registers ----------------
struct AW {
    const float* qs[2]; const float* ko[2];
    const u16* w2[2]; const u16* b2[2];
    u16* outw[2]; float* sums[2];
    int transposed[2];
};

__global__ __launch_bounds__(256, 4) void attnw6(AW a, const void* __restrict__ adj,
                                                 const u32* __restrict__ flag) {
    __shared__ float tile[32][257];
    __shared__ float wpart[4][32];
    int z = blockIdx.z;
    int tid = threadIdx.x;
    int lane = tid & 63, wv = tid >> 6;
    int jl = wv * 64 + lane;                 // j_local 0..255
    int jbase = blockIdx.x * 256;
    int j = jbase + jl;
    int p0 = blockIdx.y * 32;                // 32 rows per block
    bool f32a = flag[0] != 0;
    bool tr = a.transposed[z] != 0;
    const float* adjf = (const float*)adj;
    const u16*   adjh = (const u16*)adj;

    float kv[32];
    {
        const float4* kp = (const float4*)(a.ko[z] + (size_t)j * 32);
        #pragma unroll
        for (int qd = 0; qd < 8; qd++) {
            float4 v = kp[qd];
            kv[qd * 4 + 0] = v.x; kv[qd * 4 + 1] = v.y;
            kv[qd * 4 + 2] = v.z; kv[qd * 4 + 3] = v.w;
        }
    }
    float w2v[32];
    #pragma unroll
    for (int i2 = 0; i2 < 32; i2++) w2v[i2] = bf2f(a.w2[z][i2]);
    float b2 = bf2f(a.b2[z][0]);
    const float* qs = a.qs[z];
    u16* outw = a.outw[z];

    if (tr) {
        if (f32a) {
            const float4* src = (const float4*)(adjf + (size_t)(jbase + tid) * 2048 + p0);
            #pragma unroll
            for (int q8 = 0; q8 < 8; q8++) {
                float4 v = src[q8];
                tile[q8 * 4 + 0][tid] = v.x; tile[q8 * 4 + 1][tid] = v.y;
                tile[q8 * 4 + 2][tid] = v.z; tile[q8 * 4 + 3][tid] = v.w;
            }
        } else {
            const uint4* src = (const uint4*)(adjh + (size_t)(jbase + tid) * 2048 + p0);
            #pragma unroll
            for (int q8 = 0; q8 < 4; q8++) {
                uint4 v = src[q8];
                u32 uu[4] = {v.x, v.y, v.z, v.w};
                #pragma unroll
                for (int c = 0; c < 4; c++) {
                    tile[q8 * 8 + c * 2 + 0][tid] = bf2f((u16)(uu[c] & 0xffff));
                    tile[q8 * 8 + c * 2 + 1][tid] = bf2f((u16)(uu[c] >> 16));
                }
            }
        }
        __syncthreads();
    }

    #pragma unroll 1
    for (int pl = 0; pl < 32; pl++) {
        int row = p0 + pl;
        const float* qrow = qs + (size_t)row * 32;   // wave-uniform -> s_loads
        float s = 0.f;
        #pragma unroll
        for (int aa = 0; aa < 32; aa++)
            s += fmaxf(qrow[aa] + kv[aa], 0.f) * w2v[aa];
        s = fmaxf(s + b2, 0.f);
        float av = tr ? tile[pl][jl]
                      : (f32a ? adjf[(size_t)row * 2048 + j]
                              : bf2f(adjh[(size_t)row * 2048 + j]));
        float e = __expf(s * av);
        outw[(size_t)row * 2048 + j] = f2bf(e);
        float t = e;
        #pragma unroll
        for (int o = 32; o > 0; o >>= 1) t += __shfl_down(t, o, 64);
        if (lane == 0) wpart[wv][pl] = t;
    }
    __syncthreads();
    if (tid < 32)
        a.sums[z][(size_t)blockIdx.x * 2048 + p0 + tid] =
            wpart[0][tid] + wpart[1][tid] + wpart[2][tid] + wpart[3][tid];
}

// ---------------- MFMA GEMM v4: branch-free specialized K-loops -------------
// 512 threads (8 waves); wave w owns col-tile [w*16, w*16+16). KS compile-time,
// prefetch depth 4, last group peeled (no guards). f32 A staged raw, packed
// at use. rsmode: 0 none, 1 *rs[row], 2 *1/sum_{p<8} rs[row+p*2048]
struct GD4 {
    const void* A[4]; const u16* BT[4]; u16* C[4];
    const u16* bias[4]; const float* rs[4];
    int lda[4], ldb[4], ldc[4], coff[4], ksteps[4], act[4], araw[4], rsmode[4];
};

template<int KS, bool AF32>
__device__ inline void gcore(const void* Av, int lda, const u16* BT, int ldb,
                             int m0, int c0, int mrow, int quad, f32x4& acc) {
    const u16* A16 = (const u16*)Av;
    const float* A32 = (const float*)Av;
    size_t aoff = (size_t)(m0 + mrow) * lda + quad * 8;
    const u16* bp = BT + (size_t)(c0 + mrow) * ldb + quad * 8;
    short8 ab[4]; float4 fa[4][2]; short8 bb[4];
    #pragma unroll
    for (int i = 0; i < 4; i++) {
        if (AF32) {
            const float4* p = (const float4*)(A32 + aoff + (size_t)i * 32);
            fa[i][0] = p[0]; fa[i][1] = p[1];
        } else {
            ab[i] = *(const short8*)(A16 + aoff + (size_t)i * 32);
        }
        bb[i] = *(const short8*)(bp + (size_t)i * 32);
    }
    #pragma unroll 1
    for (int k = 0; k + 4 < KS; k += 4) {
        #pragma unroll
        for (int u = 0; u < 4; u++) {
            short8 a = AF32 ? packbf8(fa[u][0], fa[u][1]) : ab[u];
            acc = __builtin_amdgcn_mfma_f32_16x16x32_bf16(a, bb[u], acc, 0, 0, 0);
            int kn = k + u + 4;
            if (AF32) {
                const float4* p = (const float4*)(A32 + aoff + (size_t)kn * 32);
                fa[u][0] = p[0]; fa[u][1] = p[1];
            } else {
                ab[u] = *(const short8*)(A16 + aoff + (size_t)kn * 32);
            }
            bb[u] = *(const short8*)(bp + (size_t)kn * 32);
        }
    }
    #pragma unroll
    for (int u = 0; u < 4; u++) {
        short8 a = AF32 ? packbf8(fa[u][0], fa[u][1]) : ab[u];
        acc = __builtin_amdgcn_mfma_f32_16x16x32_bf16(a, bb[u], acc, 0, 0, 0);
    }
}

__global__ __launch_bounds__(512, 2) void gemm16d(GD4 g, const u32* __restrict__ flag) {
    int z = blockIdx.y;
    bool af32 = g.araw[z] && (flag[0] != 0);
    int ks = g.ksteps[z];
    int tid = threadIdx.x;
    int lane = tid & 63, wv = tid >> 6;
    int mrow = lane & 15, quad = lane >> 4;
    int m0 = blockIdx.x * 16;
    int c0 = wv * 16;
    f32x4 acc = {0.f, 0.f, 0.f, 0.f};
    const void* A = g.A[z]; int lda = g.lda[z];
    const u16* BT = g.BT[z]; int ldb = g.ldb[z];
    if (ks == 64) {
        if (af32) gcore<64, true>(A, lda, BT, ldb, m0, c0, mrow, quad, acc);
        else      gcore<64, false>(A, lda, BT, ldb, m0, c0, mrow, quad, acc);
    } else if (ks == 8) {
        gcore<8, false>(A, lda, BT, ldb, m0, c0, mrow, quad, acc);
    } else {
        gcore<4, false>(A, lda, BT, ldb, m0, c0, mrow, quad, acc);
    }

    const float* rs = g.rs[z];
    int rsmode = g.rsmode[z];
    const u16* bi = g.bias[z];
    u16* C = g.C[z];
    int ldc = g.ldc[z], coff = g.coff[z], act = g.act[z];
    int col = c0 + mrow;
    float bv = bi ? bf2f(bi[col]) : 0.f;
    #pragma unroll
    for (int r = 0; r < 4; r++) {
        int row = m0 + quad * 4 + r;
        float v = acc[r];
        if (rsmode == 1) v *= rs[row];
        else if (rsmode == 2) {
            float t = 0.f;
            #pragma unroll
            for (int p = 0; p < 8; p++) t += rs[row + p * 2048];
            v *= 1.f / t;
        }
        v += bv;
        if (act) v = seluf(v);
        C[(size_t)row * ldc + coff + col] = f2bf(v);
    }
}

// ---------------- pair gather ----------
__global__ __launch_bounds__(256) void xbuild(
    const u16* __restrict__ he, const u16* __restrict__ hp,
    const int* __restrict__ di, const int* __restrict__ dr, u16* __restrict__ X) {
    int idx = blockIdx.x * 256 + threadIdx.x;  // < B*64
    int d2 = idx & 63;
    int b = idx >> 6;
    int ia = di[b], ic = dr[b];
    u32 ue = ((const u32*)he)[ia * 64 + d2];
    u32 up = ((const u32*)hp)[ic * 64 + d2];
    float lo = bf2f((u16)(ue & 0xffff)) * bf2f((u16)(up & 0xffff));
    float hi = bf2f((u16)(ue >> 16)) * bf2f((u16)(up >> 16));
    ((u32*)X)[idx] = (u32)f2bf(lo) | ((u32)f2bf(hi) << 16);
}

// ---------------- z, sigmoid, loss (FLOAT32 out: out[0]=loss, out[1+b]=sig) --
__global__ __launch_bounds__(256) void zloss(
    const u16* __restrict__ X2, const u16* __restrict__ wpred,
    const u16* __restrict__ bpred, const int* __restrict__ labels,
    float* __restrict__ out, float* __restrict__ part) {
    __shared__ float wp[128];
    __shared__ float ls[256];
    int tid = threadIdx.x;
    if (tid < 128) wp[tid] = bf2f(wpred[tid]);
    __syncthreads();
    int b = blockIdx.x * 256 + tid;
    const uint4* xp = (const uint4*)(X2 + (size_t)b * 128);
    float z = 0.f;
    #pragma unroll
    for (int i = 0; i < 16; i++) {
        uint4 q = xp[i];
        u32 u[4] = {q.x, q.y, q.z, q.w};
        #pragma unroll
        for (int c = 0; c < 4; c++) {
            z += bf2f((u16)(u[c] & 0xffff)) * wp[i * 8 + c * 2];
            z += bf2f((u16)(u[c] >> 16)) * wp[i * 8 + c * 2 + 1];
        }
    }
    z += bf2f(bpred[0]);
    out[1 + b] = 1.f / (1.f + __expf(-z));
    float y = (float)labels[b];
    ls[tid] = fmaxf(z, 0.f) - z * y + log1pf(__expf(-fabsf(z)));
    __syncthreads();
    for (int o = 128; o > 0; o >>= 1) {
        if (tid < o) ls[tid] += ls[tid + o];
        __syncthreads();
    }
    if (tid == 0) part[blockIdx.x] = ls[0];
}

__global__ void finloss(const float* __restrict__ part, float* __restrict__ out) {
    __shared__ float s[64];
    s[threadIdx.x] = part[threadIdx.x];
    __syncthreads();
    for (int o = 32; o > 0; o >>= 1) {
        if (threadIdx.x < o) s[threadIdx.x] += s[threadIdx.x + o];
        __syncthreads();
    }
    if (threadIdx.x == 0) out[0] = s[0] * (1.f / 16384.f);
}

// ---------------- launch ----------------
extern "C" void kernel_launch(void* const* d_in, const int* in_sizes, int n_in,
                              void* d_out, int out_size, void* d_ws, size_t ws_size,
                              hipStream_t stream) {
    const void* e_p_adj = d_in[0];
    const void* e_e_adj = d_in[1];
    const void* p_p_adj = d_in[2];
    const int* in_dis  = (const int*)d_in[3];
    const int* in_drug = (const int*)d_in[4];
    const int* labels  = (const int*)d_in[5];
    float* out = (float*)d_out;

    // -------- workspace layout --------
    char* ws = (char*)d_ws;
    size_t off = 0;
    auto take = [&](size_t bytes) { char* p = ws + off; off = (off + bytes + 255) & ~(size_t)255; return p; };
    u16*   Wbuf  = (u16*)take((size_t)2048 * 2048 * 2);   // exp weights; later X+X1
    u16*   drugT = (u16*)take((size_t)128 * 2048 * 2);    // --- X2 overlays drugT..A_p ---
    u16*   disT  = (u16*)take((size_t)128 * 2048 * 2);
    float* ko_d  = (float*)take((size_t)2048 * 32 * 4);
    float* qs_d  = (float*)take((size_t)2048 * 32 * 4);
    float* ko_p  = (float*)take((size_t)2048 * 32 * 4);
    float* qs_p  = (float*)take((size_t)2048 * 32 * 4);
    u16*   A_e   = (u16*)take((size_t)2048 * 256 * 2);
    u16*   A_p   = (u16*)take((size_t)2048 * 256 * 2);
    u16*   WcTe  = (u16*)take((size_t)128 * 256 * 2);
    u16*   WcTp  = (u16*)take((size_t)128 * 256 * 2);
    u16*   W1T   = (u16*)take((size_t)128 * 128 * 2);
    u16*   W2T   = (u16*)take((size_t)128 * 128 * 2);
    u16*   b_e   = (u16*)take(256);
    u16*   b_p   = (u16*)take(256);
    u16*   h_e   = (u16*)take((size_t)2048 * 128 * 2);
    u16*   h_p   = (u16*)take((size_t)2048 * 128 * 2);
    float* dinv_e = (float*)take(2048 * 4);
    float* dinv_p = (float*)take(2048 * 4);
    float* sumsD  = (float*)take(8 * 2048 * 4);
    float* sumsP  = (float*)take(8 * 2048 * 4);
    float* part  = (float*)take(64 * 4);
    u16*   canon = (u16*)take((size_t)700000 * 2);
    u32*   flag  = (u32*)take(256);
    bool dual = (ws_size > off) && (ws_size - off) >= ((size_t)2048 * 2048 * 2 + 512);
    u16*   Wbuf2 = dual ? (u16*)take((size_t)2048 * 2048 * 2) : Wbuf;
    u16* X  = Wbuf;
    u16* X1 = Wbuf + (size_t)BB * 128;
    u16* X2 = drugT;   // 4 MB over drugT..A_p

    // -------- canonical parameter table --------
    const int segidx[NSEG] = {6, 7, 14, 18, 8, 22, 11, 24, 26, 28,
                              15, 16, 17, 19, 20, 21,
                              9, 10, 12, 13, 23, 25, 27, 29, 30, 31};
    const int segn[NSEG]   = {262144, 262144, 8192, 8192, 16384, 16384, 16384, 16384, 16384, 16384,
                              32, 32, 1, 32, 32, 1,
                              128, 128, 128, 128, 128, 128, 128, 128, 128, 1};
    CvtArgs ca;
    u16* cp[NSEG];
    {
        int o = 0;
        for (int i = 0; i < NSEG; i++) {
            ca.src[i] = d_in[segidx[i]];
            ca.off[i] = o;
            ca.n[i] = segn[i];
            cp[i] = canon + o;
            o += (segn[i] + 15) & ~15;
        }
    }
    u16 *cdemb = cp[0], *cpemb = cp[1], *cWa1d = cp[2], *cWa1p = cp[3];
    u16 *cWdg = cp[4], *cWd2 = cp[5], *cWpg = cp[6], *cWp3 = cp[7];
    u16 *cW1 = cp[8], *cW2 = cp[9];
    u16 *cba1d = cp[10], *cWa2d = cp[11], *cba2d = cp[12];
    u16 *cba1p = cp[13], *cWa2p = cp[14], *cba2p = cp[15];
    u16 *cbdg_lin = cp[16], *cbdg = cp[17], *cbpg_lin = cp[18], *cbpg = cp[19];
    u16 *cbd2 = cp[20], *cbp3 = cp[21], *cmb1 = cp[22], *cmb2 = cp[23];
    u16 *cWpred = cp[24], *cbpred = cp[25];

    // -------- 0. dtype detection + canonicalization --------
    detectk<<<1, 256, 0, stream>>>(d_in[6], flag);
    cvtk<<<dim3(64, NSEG), 256, 0, stream>>>(ca, canon, flag);

    // -------- 1. prep --------
    tpose_embs<<<dim3(4, 64, 2), dim3(32, 8), 0, stream>>>(cdemb, cpemb, disT, drugT);
    tpose_smalls<<<dim3(4, 4, 6), dim3(32, 8), 0, stream>>>(
        cW1, cW2, cWdg, cWd2, cWpg, cWp3, W1T, W2T, WcTe, WcTp);
    biasc<<<1, 128, 0, stream>>>(cbdg_lin, cbdg, cbd2, b_e, cbpg_lin, cbpg, cbp3, b_p);
    degk<<<dim3(2048, 2), 256, 0, stream>>>(e_e_adj, dinv_e, p_p_adj, dinv_p, flag);
    koqs<<<dim3(2048, 4), 128, 0, stream>>>(cdemb, cpemb, cWa1d, cba1d, cWa1p, cba1p,
                                            ko_d, qs_d, ko_p, qs_p);

    auto setd = [](GD4& g, int z, const void* A, int lda, const u16* BT, int ldb,
                   u16* C, int ldc, int coff, int ks, const u16* bi,
                   const float* rs, int act, int araw, int rm) {
        g.A[z] = A; g.lda[z] = lda; g.BT[z] = BT; g.ldb[z] = ldb;
        g.C[z] = C; g.ldc[z] = ldc; g.coff[z] = coff; g.ksteps[z] = ks;
        g.bias[z] = bi; g.rs[z] = rs; g.act[z] = act; g.araw[z] = araw; g.rsmode[z] = rm;
    };
    auto mkaw = [](const float* qs0, const float* ko0, const u16* w20, const u16* b20,
                   u16* o0, float* s0, int t0,
                   const float* qs1, const float* ko1, const u16* w21, const u16* b21,
                   u16* o1, float* s1, int t1) {
        AW a;
        a.qs[0] = qs0; a.ko[0] = ko0; a.w2[0] = w20; a.b2[0] = b20;
        a.outw[0] = o0; a.sums[0] = s0; a.transposed[0] = t0;
        a.qs[1] = qs1; a.ko[1] = ko1; a.w2[1] = w21; a.b2[1] = b21;
        a.outw[1] = o1; a.sums[1] = s1; a.transposed[1] = t1;
        return a;
    };

    // -------- 2. attention weights + aggregation GEMMs --------
    if (dual) {
        AW aw = mkaw(qs_d, ko_d, cWa2d, cba2d, Wbuf, sumsD, 0,
                     qs_p, ko_p, cWa2p, cba2p, Wbuf2, sumsP, 1);
        attnw6<<<dim3(8, 64, 2), 256, 0, stream>>>(aw, e_p_adj, flag);
        GD4 g;
        setd(g, 0, Wbuf, 2048, drugT, 2048, A_e, 256, 0, 64, nullptr, sumsD, 0, 0, 2);
        setd(g, 1, e_e_adj, 2048, disT, 2048, A_e, 256, 128, 64, nullptr, dinv_e, 0, 1, 1);
        setd(g, 2, Wbuf2, 2048, disT, 2048, A_p, 256, 0, 64, nullptr, sumsP, 0, 0, 2);
        setd(g, 3, p_p_adj, 2048, drugT, 2048, A_p, 256, 128, 64, nullptr, dinv_p, 0, 1, 1);
        gemm16d<<<dim3(128, 4), 512, 0, stream>>>(g, flag);
    } else {
        AW aw1 = mkaw(qs_d, ko_d, cWa2d, cba2d, Wbuf, sumsD, 0,
                      qs_d, ko_d, cWa2d, cba2d, Wbuf, sumsD, 0);
        attnw6<<<dim3(8, 64, 1), 256, 0, stream>>>(aw1, e_p_adj, flag);
        GD4 g1;
        setd(g1, 0, Wbuf, 2048, drugT, 2048, A_e, 256, 0, 64, nullptr, sumsD, 0, 0, 2);
        setd(g1, 1, e_e_adj, 2048, disT, 2048, A_e, 256, 128, 64, nullptr, dinv_e, 0, 1, 1);
        setd(g1, 2, Wbuf, 2048, drugT, 2048, A_e, 256, 0, 64, nullptr, sumsD, 0, 0, 2);
        setd(g1, 3, Wbuf, 2048, drugT, 2048, A_e, 256, 0, 64, nullptr, sumsD, 0, 0, 2);
        gemm16d<<<dim3(128, 2), 512, 0, stream>>>(g1, flag);
        AW aw2 = mkaw(qs_p, ko_p, cWa2p, cba2p, Wbuf, sumsP, 1,
                      qs_p, ko_p, cWa2p, cba2p, Wbuf, sumsP, 1);
        attnw6<<<dim3(8, 64, 1), 256, 0, stream>>>(aw2, e_p_adj, flag);
        GD4 g2;
        setd(g2, 0, Wbuf, 2048, disT, 2048, A_p, 256, 0, 64, nullptr, sumsP, 0, 0, 2);
        setd(g2, 1, p_p_adj, 2048, drugT, 2048, A_p, 256, 128, 64, nullptr, dinv_p, 0, 1, 1);
        setd(g2, 2, Wbuf, 2048, disT, 2048, A_p, 256, 0, 64, nullptr, sumsP, 0, 0, 2);
        setd(g2, 3, Wbuf, 2048, disT, 2048, A_p, 256, 0, 64, nullptr, sumsP, 0, 0, 2);
        gemm16d<<<dim3(128, 2), 512, 0, stream>>>(g2, flag);
    }

    // -------- 3. combine GEMMs (bias + SELU), batched ----------------------
    {
        GD4 g;
        setd(g, 0, A_e, 256, WcTe, 256, h_e, 128, 0, 8, b_e, nullptr, 1, 0, 0);
        setd(g, 1, A_p, 256, WcTp, 256, h_p, 128, 0, 8, b_p, nullptr, 1, 0, 0);
        setd(g, 2, A_e, 256, WcTe, 256, h_e, 128, 0, 8, b_e, nullptr, 1, 0, 0);
        setd(g, 3, A_e, 256, WcTe, 256, h_e, 128, 0, 8, b_e, nullptr, 1, 0, 0);
        gemm16d<<<dim3(128, 2), 512, 0, stream>>>(g, flag);
    }

    // -------- 4. pair MLP --------
    xbuild<<<4096, 256, 0, stream>>>(h_e, h_p, in_dis, in_drug, X);
    {
        GD4 g;
        setd(g, 0, X, 128, W1T, 128, X1, 128, 0, 4, cmb1, nullptr, 1, 0, 0);
        setd(g, 1, X, 128, W1T, 128, X1, 128, 0, 4, cmb1, nullptr, 1, 0, 0);
        setd(g, 2, X, 128, W1T, 128, X1, 128, 0, 4, cmb1, nullptr, 1, 0, 0);
        setd(g, 3, X, 128, W1T, 128, X1, 128, 0, 4, cmb1, nullptr, 1, 0, 0);
        gemm16d<<<dim3(1024, 1), 512, 0, stream>>>(g, flag);
    }
    {
        GD4 g;
        setd(g, 0, X1, 128, W2T, 128, X2, 128, 0, 4, cmb2, nullptr, 1, 0, 0);
        setd(g, 1, X1, 128, W2T, 128, X2, 128, 0, 4, cmb2, nullptr, 1, 0, 0);
        setd(g, 2, X1, 128, W2T, 128, X2, 128, 0, 4, cmb2, nullptr, 1, 0, 0);
        setd(g, 3, X1, 128, W2T, 128, X2, 128, 0, 4, cmb2, nullptr, 1, 0, 0);
        gemm16d<<<dim3(1024, 1), 512, 0, stream>>>(g, flag);
    }

    // -------- 5. z / sigmoid / loss --------
    zloss<<<64, 256, 0, stream>>>(X2, cWpred, cbpred, labels, out, part);
    finloss<<<1, 64, 0, stream>>>(part, out);
}

// Round 13
// 255.881 us; speedup vs baseline: 1.2974x; 1.2974x over previous
//
#include <hip/hip_runtime.h>

#define ND   2048
#define BB   16384

typedef unsigned short u16;
typedef unsigned int u32;
typedef __attribute__((ext_vector_type(8))) short short8;
typedef __attribute__((ext_vector_type(4))) float f32x4;

__device__ inline float bf2f(u16 u) {
    union { u32 i; float f; } v; v.i = ((u32)u) << 16; return v.f;
}
__device__ inline u16 f2bf(float f) {
    union { float f; u32 i; } v; v.f = f;
    u32 i = v.i + 0x7fffu + ((v.i >> 16) & 1u);
    return (u16)(i >> 16);
}
__device__ inline float seluf(float x) {
    const float sc = 1.0507009873554805f, al = 1.6732632423543772f;
    return x > 0.f ? sc * x : sc * al * expm1f(x);
}
__device__ inline short8 packbf8(float4 f0, float4 f1) {
    short8 a;
    a[0] = (short)f2bf(f0.x); a[1] = (short)f2bf(f0.y);
    a[2] = (short)f2bf(f0.z); a[3] = (short)f2bf(f0.w);
    a[4] = (short)f2bf(f1.x); a[5] = (short)f2bf(f1.y);
    a[6] = (short)f2bf(f1.z); a[7] = (short)f2bf(f1.w);
    return a;
}

// ---------------- dtype sniffer ----------------
__global__ void detectk(const void* __restrict__ demb, u32* __restrict__ flag) {
    const u16* p = (const u16*)demb;
    int tid = threadIdx.x;  // 256
    int sane = 0;
    #pragma unroll
    for (int i = 0; i < 2; i++) {
        u16 u = p[4 * tid + 2 * i];
        int e = (u >> 7) & 0xFF;
        if (u == 0 || (e >= 0x66 && e <= 0x8C)) sane++;
    }
    __shared__ int red[256];
    red[tid] = sane; __syncthreads();
    for (int o = 128; o > 0; o >>= 1) {
        if (tid < o) red[tid] += red[tid + o];
        __syncthreads();
    }
    if (tid == 0) flag[0] = (red[0] < 300) ? 1u : 0u;
}

// ---------------- canonical bf16 conversion (26 segments, one launch) -------
#define NSEG 26
struct CvtArgs { const void* src[NSEG]; int off[NSEG]; int n[NSEG]; };

__global__ __launch_bounds__(256) void cvtk(CvtArgs a, u16* __restrict__ base,
                                            const u32* __restrict__ flag) {
    int seg = blockIdx.y;
    int n = a.n[seg];
    const void* s = a.src[seg];
    u16* d = base + a.off[seg];
    bool f32 = flag[0] != 0;
    int stride = gridDim.x * blockDim.x;
    for (int i = blockIdx.x * blockDim.x + threadIdx.x; i < n; i += stride)
        d[i] = f32 ? f2bf(((const float*)s)[i]) : ((const u16*)s)[i];
}

// ---------------- transpose (bf16, tiled 32x32) ----------------
__device__ inline void tpose_body(const u16* in, int R, int C,
                                  u16* out, int ldo, int ooff,
                                  u16 (*tile)[33]) {
    int c0 = blockIdx.x * 32, r0 = blockIdx.y * 32;
    int x = c0 + threadIdx.x;
    for (int i = threadIdx.y; i < 32; i += 8) {
        int r = r0 + i;
        tile[i][threadIdx.x] = (r < R && x < C) ? in[(size_t)r * C + x] : (u16)0;
    }
    __syncthreads();
    int rr = r0 + threadIdx.x;
    for (int i = threadIdx.y; i < 32; i += 8) {
        int cc = c0 + i;
        if (cc < C && rr < R) out[(size_t)cc * ldo + ooff + rr] = tile[threadIdx.x][i];
    }
}

__global__ void tpose_embs(const u16* __restrict__ demb, const u16* __restrict__ pemb,
                           u16* __restrict__ disT, u16* __restrict__ drugT) {
    __shared__ u16 tile[32][33];
    if (blockIdx.z == 0) tpose_body(demb, ND, 128, disT, ND, 0, tile);
    else                 tpose_body(pemb, ND, 128, drugT, ND, 0, tile);
}

__global__ void tpose_smalls(const u16* s0, const u16* s1, const u16* s2,
                             const u16* s3, const u16* s4, const u16* s5,
                             u16* W1T, u16* W2T, u16* WcTe, u16* WcTp) {
    __shared__ u16 tile[32][33];
    const u16* in; u16* out; int ldo, ooff;
    switch (blockIdx.z) {
        case 0:  in = s0; out = W1T;  ldo = 128; ooff = 0;   break;
        case 1:  in = s1; out = W2T;  ldo = 128; ooff = 0;   break;
        case 2:  in = s2; out = WcTe; ldo = 256; ooff = 0;   break;
        case 3:  in = s3; out = WcTe; ldo = 256; ooff = 128; break;
        case 4:  in = s4; out = WcTp; ldo = 256; ooff = 0;   break;
        default: in = s5; out = WcTp; ldo = 256; ooff = 128; break;
    }
    tpose_body(in, 128, 128, out, ldo, ooff, tile);
}

// ---------------- combined biases ----------------
__global__ void biasc(const u16* a0, const u16* a1, const u16* a2, u16* o0,
                      const u16* b0, const u16* b1, const u16* b2, u16* o1) {
    int t = threadIdx.x;  // 128
    o0[t] = f2bf(bf2f(a0[t]) + bf2f(a1[t]) + bf2f(a2[t]));
    o1[t] = f2bf(bf2f(b0[t]) + bf2f(b1[t]) + bf2f(b2[t]));
}

// ---------------- inverse degree ----------------
__global__ __launch_bounds__(256) void degk(
    const void* __restrict__ e_e, float* __restrict__ dinv_e,
    const void* __restrict__ p_p, float* __restrict__ dinv_p,
    const u32* __restrict__ flag) {
    int row = blockIdx.x, tid = threadIdx.x;
    const void* ab = blockIdx.y ? p_p : e_e;
    float* o = blockIdx.y ? dinv_p : dinv_e;
    bool f32 = flag[0] != 0;
    float s = 0.f;
    if (f32) {
        const float4* a4 = (const float4*)((const float*)ab + (size_t)row * 2048) + tid * 2;
        float4 v0 = a4[0], v1 = a4[1];
        s = v0.x + v0.y + v0.z + v0.w + v1.x + v1.y + v1.z + v1.w;
    } else {
        const uint4* a4 = (const uint4*)((const u16*)ab + (size_t)row * 2048) + tid;
        uint4 v = a4[0];
        u32 u[4] = {v.x, v.y, v.z, v.w};
        #pragma unroll
        for (int c = 0; c < 4; c++)
            s += bf2f((u16)(u[c] & 0xffff)) + bf2f((u16)(u[c] >> 16));
    }
    __shared__ float red[256];
    red[tid] = s; __syncthreads();
    for (int ofs = 128; ofs > 0; ofs >>= 1) {
        if (tid < ofs) red[tid] += red[tid + ofs];
        __syncthreads();
    }
    if (tid == 0) o[row] = 1.f / (red[0] + 1e-8f);
}

// ---------------- ko / qs projections ----------
__global__ __launch_bounds__(128) void koqs(
    const u16* __restrict__ demb, const u16* __restrict__ pemb,
    const u16* __restrict__ Wa1d, const u16* __restrict__ ba1d,
    const u16* __restrict__ Wa1p, const u16* __restrict__ ba1p,
    float* __restrict__ ko_d, float* __restrict__ qs_d,
    float* __restrict__ ko_p, float* __restrict__ qs_p) {
    int row = blockIdx.x, m = blockIdx.y, tid = threadIdx.x;
    const u16* src; const u16* W; const u16* bias; float* out;
    switch (m) {
        case 0:  src = pemb; W = Wa1d;            bias = nullptr; out = ko_d; break;
        case 1:  src = demb; W = Wa1d + 128 * 32; bias = ba1d;    out = qs_d; break;
        case 2:  src = demb; W = Wa1p;            bias = nullptr; out = ko_p; break;
        default: src = pemb; W = Wa1p + 128 * 32; bias = ba1p;    out = qs_p; break;
    }
    __shared__ float x[128];
    __shared__ float red[128];
    x[tid] = bf2f(src[(size_t)row * 128 + tid]);
    __syncthreads();
    int a = tid & 31, part = tid >> 5;
    float s = 0.f;
    #pragma unroll
    for (int k = 0; k < 32; k++) s += x[part * 32 + k] * bf2f(W[(part * 32 + k) * 32 + a]);
    red[tid] = s;
    __syncthreads();
    if (part == 0) {
        float t = red[a] + red[a + 32] + red[a + 64] + red[a + 96];
        if (bias) t += bf2f(bias[a]);
        out[(size_t)row * 32 + a] = t;
    }
}

// ---------------- attention v6: lane-owns-j, ko in registers ----------------
struct AW {
    const float* qs[2]; const float* ko[2];
    const u16* w2[2]; const u16* b2[2];
    u16* outw[2]; float* sums[2];
    int transposed[2];
};

__global__ __launch_bounds__(256, 4) void attnw6(AW a, const void* __restrict__ adj,
                                                 const u32* __restrict__ flag) {
    __shared__ float tile[32][257];
    __shared__ float wpart[4][32];
    int z = blockIdx.z;
    int tid = threadIdx.x;
    int lane = tid & 63, wv = tid >> 6;
    int jl = wv * 64 + lane;                 // j_local 0..255
    int jbase = blockIdx.x * 256;
    int j = jbase + jl;
    int p0 = blockIdx.y * 32;                // 32 rows per block
    bool f32a = flag[0] != 0;
    bool tr = a.transposed[z] != 0;
    const float* adjf = (const float*)adj;
    const u16*   adjh = (const u16*)adj;

    float kv[32];
    {
        const float4* kp = (const float4*)(a.ko[z] + (size_t)j * 32);
        #pragma unroll
        for (int qd = 0; qd < 8; qd++) {
            float4 v = kp[qd];
            kv[qd * 4 + 0] = v.x; kv[qd * 4 + 1] = v.y;
            kv[qd * 4 + 2] = v.z; kv[qd * 4 + 3] = v.w;
        }
    }
    float w2v[32];
    #pragma unroll
    for (int i2 = 0; i2 < 32; i2++) w2v[i2] = bf2f(a.w2[z][i2]);
    float b2 = bf2f(a.b2[z][0]);
    const float* qs = a.qs[z];
    u16* outw = a.outw[z];

    if (tr) {
        if (f32a) {
            const float4* src = (const float4*)(adjf + (size_t)(jbase + tid) * 2048 + p0);
            #pragma unroll
            for (int q8 = 0; q8 < 8; q8++) {
                float4 v = src[q8];
                tile[q8 * 4 + 0][tid] = v.x; tile[q8 * 4 + 1][tid] = v.y;
                tile[q8 * 4 + 2][tid] = v.z; tile[q8 * 4 + 3][tid] = v.w;
            }
        } else {
            const uint4* src = (const uint4*)(adjh + (size_t)(jbase + tid) * 2048 + p0);
            #pragma unroll
            for (int q8 = 0; q8 < 4; q8++) {
                uint4 v = src[q8];
                u32 uu[4] = {v.x, v.y, v.z, v.w};
                #pragma unroll
                for (int c = 0; c < 4; c++) {
                    tile[q8 * 8 + c * 2 + 0][tid] = bf2f((u16)(uu[c] & 0xffff));
                    tile[q8 * 8 + c * 2 + 1][tid] = bf2f((u16)(uu[c] >> 16));
                }
            }
        }
        __syncthreads();
    }

    #pragma unroll 1
    for (int pl = 0; pl < 32; pl++) {
        int row = p0 + pl;
        const float* qrow = qs + (size_t)row * 32;   // wave-uniform -> s_loads
        float s = 0.f;
        #pragma unroll
        for (int aa = 0; aa < 32; aa++)
            s += fmaxf(qrow[aa] + kv[aa], 0.f) * w2v[aa];
        s = fmaxf(s + b2, 0.f);
        float av = tr ? tile[pl][jl]
                      : (f32a ? adjf[(size_t)row * 2048 + j]
                              : bf2f(adjh[(size_t)row * 2048 + j]));
        float e = __expf(s * av);
        outw[(size_t)row * 2048 + j] = f2bf(e);
        float t = e;
        #pragma unroll
        for (int o = 32; o > 0; o >>= 1) t += __shfl_down(t, o, 64);
        if (lane == 0) wpart[wv][pl] = t;
    }
    __syncthreads();
    if (tid < 32)
        a.sums[z][(size_t)blockIdx.x * 2048 + p0 + tid] =
            wpart[0][tid] + wpart[1][tid] + wpart[2][tid] + wpart[3][tid];
}

// ---------------- MFMA GEMM v5: canonical LDS-tiled (guide §5) --------------
// block 256 thr (4 waves). Tile M=16 x N=128 x BK=128. A/B staged in padded
// LDS; f32 A packed to bf16 during staging. Wave w owns cols [w*32,w*32+32)
// as two 16x16 accumulators. Staging loads for iter k+1 overlap compute of k.
// rsmode: 0 none, 1 *rs[row], 2 *1/sum_{p<8} rs[row+p*2048]
struct GD4 {
    const void* A[4]; const u16* BT[4]; u16* C[4];
    const u16* bias[4]; const float* rs[4];
    int lda[4], ldb[4], ldc[4], coff[4], kiters[4], act[4], araw[4], rsmode[4];
};

#define PADK 136

__global__ __launch_bounds__(256, 2) void gemmL(GD4 g, const u32* __restrict__ flag) {
    __shared__ __align__(16) u16 As[16][PADK];
    __shared__ __align__(16) u16 Bs[128][PADK];
    int z = blockIdx.y;
    bool af32 = g.araw[z] && (flag[0] != 0);
    const void* A = g.A[z];
    const u16* BT = g.BT[z];
    int lda = g.lda[z], ldb = g.ldb[z];
    int kiters = g.kiters[z];
    int tid = threadIdx.x;
    int lane = tid & 63, wv = tid >> 6;
    int mrow = lane & 15, quad = lane >> 4;
    int m0 = blockIdx.x * 16;
    int c0 = wv * 32;
    int sr = tid >> 4, sk = (tid & 15) * 8;   // staging row / k-offset
    f32x4 acc0 = {0.f, 0.f, 0.f, 0.f}, acc1 = {0.f, 0.f, 0.f, 0.f};

    short8 ra, rb[8];
    auto ldstage = [&](int kb) {
        if (af32) {
            const float* A32 = (const float*)A;
            const float4* p = (const float4*)(A32 + (size_t)(m0 + sr) * lda + kb + sk);
            float4 f0 = p[0], f1 = p[1];
            ra = packbf8(f0, f1);
        } else {
            ra = *(const short8*)((const u16*)A + (size_t)(m0 + sr) * lda + kb + sk);
        }
        const u16* bbase = BT + (size_t)sr * ldb + kb + sk;
        #pragma unroll
        for (int i = 0; i < 8; i++)
            rb[i] = *(const short8*)(bbase + (size_t)i * 16 * ldb);
    };
    auto ststage = [&]() {
        *(short8*)(&As[sr][sk]) = ra;
        #pragma unroll
        for (int i = 0; i < 8; i++)
            *(short8*)(&Bs[i * 16 + sr][sk]) = rb[i];
    };
    auto compute = [&]() {
        #pragma unroll
        for (int ks = 0; ks < 4; ks++) {
            short8 af = *(const short8*)(&As[mrow][ks * 32 + quad * 8]);
            short8 b0 = *(const short8*)(&Bs[c0 + mrow][ks * 32 + quad * 8]);
            short8 b1 = *(const short8*)(&Bs[c0 + 16 + mrow][ks * 32 + quad * 8]);
            acc0 = __builtin_amdgcn_mfma_f32_16x16x32_bf16(af, b0, acc0, 0, 0, 0);
            acc1 = __builtin_amdgcn_mfma_f32_16x16x32_bf16(af, b1, acc1, 0, 0, 0);
        }
    };

    ldstage(0);
    #pragma unroll 1
    for (int it = 0; it < kiters - 1; ++it) {
        ststage();
        __syncthreads();
        ldstage((it + 1) * 128);   // overlaps compute below
        compute();
        __syncthreads();
    }
    ststage();
    __syncthreads();
    compute();

    const float* rs = g.rs[z];
    int rsmode = g.rsmode[z];
    const u16* bi = g.bias[z];
    u16* C = g.C[z];
    int ldc = g.ldc[z], coff = g.coff[z], act = g.act[z];
    int n0 = c0 + mrow, n1 = n0 + 16;
    float bv0 = bi ? bf2f(bi[n0]) : 0.f;
    float bv1 = bi ? bf2f(bi[n1]) : 0.f;
    #pragma unroll
    for (int r = 0; r < 4; r++) {
        int row = m0 + quad * 4 + r;
        float v0 = acc0[r], v1 = acc1[r];
        if (rsmode == 1) { float sc = rs[row]; v0 *= sc; v1 *= sc; }
        else if (rsmode == 2) {
            float t = 0.f;
            #pragma unroll
            for (int p = 0; p < 8; p++) t += rs[row + p * 2048];
            float sc = 1.f / t;
            v0 *= sc; v1 *= sc;
        }
        v0 += bv0; v1 += bv1;
        if (act) { v0 = seluf(v0); v1 = seluf(v1); }
        C[(size_t)row * ldc + coff + n0] = f2bf(v0);
        C[(size_t)row * ldc + coff + n1] = f2bf(v1);
    }
}

// ---------------- pair gather ----------
__global__ __launch_bounds__(256) void xbuild(
    const u16* __restrict__ he, const u16* __restrict__ hp,
    const int* __restrict__ di, const int* __restrict__ dr, u16* __restrict__ X) {
    int idx = blockIdx.x * 256 + threadIdx.x;  // < B*64
    int d2 = idx & 63;
    int b = idx >> 6;
    int ia = di[b], ic = dr[b];
    u32 ue = ((const u32*)he)[ia * 64 + d2];
    u32 up = ((const u32*)hp)[ic * 64 + d2];
    float lo = bf2f((u16)(ue & 0xffff)) * bf2f((u16)(up & 0xffff));
    float hi = bf2f((u16)(ue >> 16)) * bf2f((u16)(up >> 16));
    ((u32*)X)[idx] = (u32)f2bf(lo) | ((u32)f2bf(hi) << 16);
}

// ---------------- z, sigmoid, loss (FLOAT32 out: out[0]=loss, out[1+b]=sig) --
__global__ __launch_bounds__(256) void zloss(
    const u16* __restrict__ X2, const u16* __restrict__ wpred,
    const u16* __restrict__ bpred, const int* __restrict__ labels,
    float* __restrict__ out, float* __restrict__ part) {
    __shared__ float wp[128];
    __shared__ float ls[256];
    int tid = threadIdx.x;
    if (tid < 128) wp[tid] = bf2f(wpred[tid]);
    __syncthreads();
    int b = blockIdx.x * 256 + tid;
    const uint4* xp = (const uint4*)(X2 + (size_t)b * 128);
    float z = 0.f;
    #pragma unroll
    for (int i = 0; i < 16; i++) {
        uint4 q = xp[i];
        u32 u[4] = {q.x, q.y, q.z, q.w};
        #pragma unroll
        for (int c = 0; c < 4; c++) {
            z += bf2f((u16)(u[c] & 0xffff)) * wp[i * 8 + c * 2];
            z += bf2f((u16)(u[c] >> 16)) * wp[i * 8 + c * 2 + 1];
        }
    }
    z += bf2f(bpred[0]);
    out[1 + b] = 1.f / (1.f + __expf(-z));
    float y = (float)labels[b];
    ls[tid] = fmaxf(z, 0.f) - z * y + log1pf(__expf(-fabsf(z)));
    __syncthreads();
    for (int o = 128; o > 0; o >>= 1) {
        if (tid < o) ls[tid] += ls[tid + o];
        __syncthreads();
    }
    if (tid == 0) part[blockIdx.x] = ls[0];
}

__global__ void finloss(const float* __restrict__ part, float* __restrict__ out) {
    __shared__ float s[64];
    s[threadIdx.x] = part[threadIdx.x];
    __syncthreads();
    for (int o = 32; o > 0; o >>= 1) {
        if (threadIdx.x < o) s[threadIdx.x] += s[threadIdx.x + o];
        __syncthreads();
    }
    if (threadIdx.x == 0) out[0] = s[0] * (1.f / 16384.f);
}

// ---------------- launch ----------------
extern "C" void kernel_launch(void* const* d_in, const int* in_sizes, int n_in,
                              void* d_out, int out_size, void* d_ws, size_t ws_size,
                              hipStream_t stream) {
    const void* e_p_adj = d_in[0];
    const void* e_e_adj = d_in[1];
    const void* p_p_adj = d_in[2];
    const int* in_dis  = (const int*)d_in[3];
    const int* in_drug = (const int*)d_in[4];
    const int* labels  = (const int*)d_in[5];
    float* out = (float*)d_out;

    // -------- workspace layout --------
    char* ws = (char*)d_ws;
    size_t off = 0;
    auto take = [&](size_t bytes) { char* p = ws + off; off = (off + bytes + 255) & ~(size_t)255; return p; };
    u16*   Wbuf  = (u16*)take((size_t)2048 * 2048 * 2);   // exp weights; later X+X1
    u16*   drugT = (u16*)take((size_t)128 * 2048 * 2);    // --- X2 overlays drugT..A_p ---
    u16*   disT  = (u16*)take((size_t)128 * 2048 * 2);
    float* ko_d  = (float*)take((size_t)2048 * 32 * 4);
    float* qs_d  = (float*)take((size_t)2048 * 32 * 4);
    float* ko_p  = (float*)take((size_t)2048 * 32 * 4);
    float* qs_p  = (float*)take((size_t)2048 * 32 * 4);
    u16*   A_e   = (u16*)take((size_t)2048 * 256 * 2);
    u16*   A_p   = (u16*)take((size_t)2048 * 256 * 2);
    u16*   WcTe  = (u16*)take((size_t)128 * 256 * 2);
    u16*   WcTp  = (u16*)take((size_t)128 * 256 * 2);
    u16*   W1T   = (u16*)take((size_t)128 * 128 * 2);
    u16*   W2T   = (u16*)take((size_t)128 * 128 * 2);
    u16*   b_e   = (u16*)take(256);
    u16*   b_p   = (u16*)take(256);
    u16*   h_e   = (u16*)take((size_t)2048 * 128 * 2);
    u16*   h_p   = (u16*)take((size_t)2048 * 128 * 2);
    float* dinv_e = (float*)take(2048 * 4);
    float* dinv_p = (float*)take(2048 * 4);
    float* sumsD  = (float*)take(8 * 2048 * 4);
    float* sumsP  = (float*)take(8 * 2048 * 4);
    float* part  = (float*)take(64 * 4);
    u16*   canon = (u16*)take((size_t)700000 * 2);
    u32*   flag  = (u32*)take(256);
    bool dual = (ws_size > off) && (ws_size - off) >= ((size_t)2048 * 2048 * 2 + 512);
    u16*   Wbuf2 = dual ? (u16*)take((size_t)2048 * 2048 * 2) : Wbuf;
    u16* X  = Wbuf;
    u16* X1 = Wbuf + (size_t)BB * 128;
    u16* X2 = drugT;   // 4 MB over drugT..A_p

    // -------- canonical parameter table --------
    const int segidx[NSEG] = {6, 7, 14, 18, 8, 22, 11, 24, 26, 28,
                              15, 16, 17, 19, 20, 21,
                              9, 10, 12, 13, 23, 25, 27, 29, 30, 31};
    const int segn[NSEG]   = {262144, 262144, 8192, 8192, 16384, 16384, 16384, 16384, 16384, 16384,
                              32, 32, 1, 32, 32, 1,
                              128, 128, 128, 128, 128, 128, 128, 128, 128, 1};
    CvtArgs ca;
    u16* cp[NSEG];
    {
        int o = 0;
        for (int i = 0; i < NSEG; i++) {
            ca.src[i] = d_in[segidx[i]];
            ca.off[i] = o;
            ca.n[i] = segn[i];
            cp[i] = canon + o;
            o += (segn[i] + 15) & ~15;
        }
    }
    u16 *cdemb = cp[0], *cpemb = cp[1], *cWa1d = cp[2], *cWa1p = cp[3];
    u16 *cWdg = cp[4], *cWd2 = cp[5], *cWpg = cp[6], *cWp3 = cp[7];
    u16 *cW1 = cp[8], *cW2 = cp[9];
    u16 *cba1d = cp[10], *cWa2d = cp[11], *cba2d = cp[12];
    u16 *cba1p = cp[13], *cWa2p = cp[14], *cba2p = cp[15];
    u16 *cbdg_lin = cp[16], *cbdg = cp[17], *cbpg_lin = cp[18], *cbpg = cp[19];
    u16 *cbd2 = cp[20], *cbp3 = cp[21], *cmb1 = cp[22], *cmb2 = cp[23];
    u16 *cWpred = cp[24], *cbpred = cp[25];

    // -------- 0. dtype detection + canonicalization --------
    detectk<<<1, 256, 0, stream>>>(d_in[6], flag);
    cvtk<<<dim3(64, NSEG), 256, 0, stream>>>(ca, canon, flag);

    // -------- 1. prep --------
    tpose_embs<<<dim3(4, 64, 2), dim3(32, 8), 0, stream>>>(cdemb, cpemb, disT, drugT);
    tpose_smalls<<<dim3(4, 4, 6), dim3(32, 8), 0, stream>>>(
        cW1, cW2, cWdg, cWd2, cWpg, cWp3, W1T, W2T, WcTe, WcTp);
    biasc<<<1, 128, 0, stream>>>(cbdg_lin, cbdg, cbd2, b_e, cbpg_lin, cbpg, cbp3, b_p);
    degk<<<dim3(2048, 2), 256, 0, stream>>>(e_e_adj, dinv_e, p_p_adj, dinv_p, flag);
    koqs<<<dim3(2048, 4), 128, 0, stream>>>(cdemb, cpemb, cWa1d, cba1d, cWa1p, cba1p,
                                            ko_d, qs_d, ko_p, qs_p);

    auto setd = [](GD4& g, int z, const void* A, int lda, const u16* BT, int ldb,
                   u16* C, int ldc, int coff, int ki, const u16* bi,
                   const float* rs, int act, int araw, int rm) {
        g.A[z] = A; g.lda[z] = lda; g.BT[z] = BT; g.ldb[z] = ldb;
        g.C[z] = C; g.ldc[z] = ldc; g.coff[z] = coff; g.kiters[z] = ki;
        g.bias[z] = bi; g.rs[z] = rs; g.act[z] = act; g.araw[z] = araw; g.rsmode[z] = rm;
    };
    auto mkaw = [](const float* qs0, const float* ko0, const u16* w20, const u16* b20,
                   u16* o0, float* s0, int t0,
                   const float* qs1, const float* ko1, const u16* w21, const u16* b21,
                   u16* o1, float* s1, int t1) {
        AW a;
        a.qs[0] = qs0; a.ko[0] = ko0; a.w2[0] = w20; a.b2[0] = b20;
        a.outw[0] = o0; a.sums[0] = s0; a.transposed[0] = t0;
        a.qs[1] = qs1; a.ko[1] = ko1; a.w2[1] = w21; a.b2[1] = b21;
        a.outw[1] = o1; a.sums[1] = s1; a.transposed[1] = t1;
        return a;
    };

    // -------- 2. attention weights + aggregation GEMMs --------
    if (dual) {
        AW aw = mkaw(qs_d, ko_d, cWa2d, cba2d, Wbuf, sumsD, 0,
                     qs_p, ko_p, cWa2p, cba2p, Wbuf2, sumsP, 1);
        attnw6<<<dim3(8, 64, 2), 256, 0, stream>>>(aw, e_p_adj, flag);
        GD4 g;
        setd(g, 0, Wbuf, 2048, drugT, 2048, A_e, 256, 0, 16, nullptr, sumsD, 0, 0, 2);
        setd(g, 1, e_e_adj, 2048, disT, 2048, A_e, 256, 128, 16, nullptr, dinv_e, 0, 1, 1);
        setd(g, 2, Wbuf2, 2048, disT, 2048, A_p, 256, 0, 16, nullptr, sumsP, 0, 0, 2);
        setd(g, 3, p_p_adj, 2048, drugT, 2048, A_p, 256, 128, 16, nullptr, dinv_p, 0, 1, 1);
        gemmL<<<dim3(128, 4), 256, 0, stream>>>(g, flag);
    } else {
        AW aw1 = mkaw(qs_d, ko_d, cWa2d, cba2d, Wbuf, sumsD, 0,
                      qs_d, ko_d, cWa2d, cba2d, Wbuf, sumsD, 0);
        attnw6<<<dim3(8, 64, 1), 256, 0, stream>>>(aw1, e_p_adj, flag);
        GD4 g1;
        setd(g1, 0, Wbuf, 2048, drugT, 2048, A_e, 256, 0, 16, nullptr, sumsD, 0, 0, 2);
        setd(g1, 1, e_e_adj, 2048, disT, 2048, A_e, 256, 128, 16, nullptr, dinv_e, 0, 1, 1);
        setd(g1, 2, Wbuf, 2048, drugT, 2048, A_e, 256, 0, 16, nullptr, sumsD, 0, 0, 2);
        setd(g1, 3, Wbuf, 2048, drugT, 2048, A_e, 256, 0, 16, nullptr, sumsD, 0, 0, 2);
        gemmL<<<dim3(128, 2), 256, 0, stream>>>(g1, flag);
        AW aw2 = mkaw(qs_p, ko_p, cWa2p, cba2p, Wbuf, sumsP, 1,
                      qs_p, ko_p, cWa2p, cba2p, Wbuf, sumsP, 1);
        attnw6<<<dim3(8, 64, 1), 256, 0, stream>>>(aw2, e_p_adj, flag);
        GD4 g2;
        setd(g2, 0, Wbuf, 2048, disT, 2048, A_p, 256, 0, 16, nullptr, sumsP, 0, 0, 2);
        setd(g2, 1, p_p_adj, 2048, drugT, 2048, A_p, 256, 128, 16, nullptr, dinv_p, 0, 1, 1);
        setd(g2, 2, Wbuf, 2048, disT, 2048, A_p, 256, 0, 16, nullptr, sumsP, 0, 0, 2);
        setd(g2, 3, Wbuf, 2048, disT, 2048, A_p, 256, 0, 16, nullptr, sumsP, 0, 0, 2);
        gemmL<<<dim3(128, 2), 256, 0, stream>>>(g2, flag);
    }

    // -------- 3. combine GEMMs (bias + SELU), batched ----------------------
    {
        GD4 g;
        setd(g, 0, A_e, 256, WcTe, 256, h_e, 128, 0, 2, b_e, nullptr, 1, 0, 0);
        setd(g, 1, A_p, 256, WcTp, 256, h_p, 128, 0, 2, b_p, nullptr, 1, 0, 0);
        setd(g, 2, A_e, 256, WcTe, 256, h_e, 128, 0, 2, b_e, nullptr, 1, 0, 0);
        setd(g, 3, A_e, 256, WcTe, 256, h_e, 128, 0, 2, b_e, nullptr, 1, 0, 0);
        gemmL<<<dim3(128, 2), 256, 0, stream>>>(g, flag);
    }

    // -------- 4. pair MLP --------
    xbuild<<<4096, 256, 0, stream>>>(h_e, h_p, in_dis, in_drug, X);
    {
        GD4 g;
        setd(g, 0, X, 128, W1T, 128, X1, 128, 0, 1, cmb1, nullptr, 1, 0, 0);
        setd(g, 1, X, 128, W1T, 128, X1, 128, 0, 1, cmb1, nullptr, 1, 0, 0);
        setd(g, 2, X, 128, W1T, 128, X1, 128, 0, 1, cmb1, nullptr, 1, 0, 0);
        setd(g, 3, X, 128, W1T, 128, X1, 128, 0, 1, cmb1, nullptr, 1, 0, 0);
        gemmL<<<dim3(1024, 1), 256, 0, stream>>>(g, flag);
    }
    {
        GD4 g;
        setd(g, 0, X1, 128, W2T, 128, X2, 128, 0, 1, cmb2, nullptr, 1, 0, 0);
        setd(g, 1, X1, 128, W2T, 128, X2, 128, 0, 1, cmb2, nullptr, 1, 0, 0);
        setd(g, 2, X1, 128, W2T, 128, X2, 128, 0, 1, cmb2, nullptr, 1, 0, 0);
        setd(g, 3, X1, 128, W2T, 128, X2, 128, 0, 1, cmb2, nullptr, 1, 0, 0);
        gemmL<<<dim3(1024, 1), 256, 0, stream>>>(g, flag);
    }

    // -------- 5. z / sigmoid / loss --------
    zloss<<<64, 256, 0, stream>>>(X2, cWpred, cbpred, labels, out, part);
    finloss<<<1, 64, 0, stream>>>(part, out);
}